// Round 1
// baseline (1160.175 us; speedup 1.0000x reference)
//
#include <hip/hip_runtime.h>

#define N_NODES 50000
#define N_EDGES 600000
#define CH 128

// ---------------------------------------------------------------------------
// K1: agg (=d_out) <- x  (self-loop contribution), cnt <- 1
// ---------------------------------------------------------------------------
__global__ __launch_bounds__(256) void k_init(const float* __restrict__ x,
                                              float* __restrict__ agg,
                                              float* __restrict__ cnt) {
    int i = blockIdx.x * 256 + threadIdx.x;
    const int NV4 = N_NODES * (CH / 4);  // 1,600,000 float4
    if (i < NV4) ((float4*)agg)[i] = ((const float4*)x)[i];
    if (i < N_NODES) cnt[i] = 1.0f;
}

// ---------------------------------------------------------------------------
// K2: per-edge scatter-add of raw features: agg[dst] += x[src]; cnt[dst] += 1
// 32 lanes per edge, float4 per lane (128 ch).
// ---------------------------------------------------------------------------
__global__ __launch_bounds__(256) void k_edges(const float* __restrict__ x,
                                               const int* __restrict__ ei,
                                               float* __restrict__ agg,
                                               float* __restrict__ cnt) {
    int g = blockIdx.x * 256 + threadIdx.x;
    int e = g >> 5;
    int lane = g & 31;
    if (e >= N_EDGES) return;
    int src = ei[e];            // edge_index[0][e]
    int dst = ei[N_EDGES + e];  // edge_index[1][e]
    float4 v = ((const float4*)(x + (size_t)src * CH))[lane];
    float* a = agg + (size_t)dst * CH + lane * 4;
    unsafeAtomicAdd(a + 0, v.x);
    unsafeAtomicAdd(a + 1, v.y);
    unsafeAtomicAdd(a + 2, v.z);
    unsafeAtomicAdd(a + 3, v.w);
    if (lane == 0) unsafeAtomicAdd(cnt + dst, 1.0f);
}

// ---------------------------------------------------------------------------
// K3: out[n] = relu( (agg[n] @ W) * (1/cnt[n]) + bias ), in-place on d_out.
// Block = 256 threads, tile = 32 rows x 128 cols; thread tile = 4x4.
// H tile staged in LDS (required for in-place correctness: all reads of the
// block's rows complete before any write). W streamed from global (64 KB,
// L2-resident, broadcast loads within wave).
// ---------------------------------------------------------------------------
constexpr int ROWS = 32;
__global__ __launch_bounds__(256) void k_gemm(float* __restrict__ out,
                                              const float* __restrict__ Wm,
                                              const float* __restrict__ bias,
                                              const float* __restrict__ cnt) {
    __shared__ float Hs[ROWS * CH];  // 16 KB
    const int t = threadIdx.x;
    const int row0 = blockIdx.x * ROWS;

    // stage H tile (1024 float4)
    {
        float4* H4 = (float4*)Hs;
        #pragma unroll
        for (int i = 0; i < 4; ++i) {
            int idx = t + 256 * i;
            int r = row0 + (idx >> 5);  // 32 float4 per row
            float4 v = make_float4(0.f, 0.f, 0.f, 0.f);
            if (r < N_NODES) v = ((const float4*)out)[(size_t)r * 32 + (idx & 31)];
            H4[idx] = v;
        }
    }
    __syncthreads();

    const int cx = t & 31;   // col group: cols 4*cx..4*cx+3
    const int ry = t >> 5;   // row group: rows 4*ry..4*ry+3
    const int c0 = cx * 4;
    const int r0 = ry * 4;

    float acc[4][4] = {};
    for (int k = 0; k < CH; k += 4) {
        float4 h[4];
        #pragma unroll
        for (int r = 0; r < 4; ++r)
            h[r] = *(const float4*)&Hs[(r0 + r) * CH + k];  // 2-way broadcast, free
        #pragma unroll
        for (int kk = 0; kk < 4; ++kk) {
            float4 w = ((const float4*)(Wm + (size_t)(k + kk) * CH))[cx];
            #pragma unroll
            for (int r = 0; r < 4; ++r) {
                float hv = ((const float*)&h[r])[kk];
                acc[r][0] = fmaf(hv, w.x, acc[r][0]);
                acc[r][1] = fmaf(hv, w.y, acc[r][1]);
                acc[r][2] = fmaf(hv, w.z, acc[r][2]);
                acc[r][3] = fmaf(hv, w.w, acc[r][3]);
            }
        }
    }

    float4 bv = ((const float4*)bias)[cx];
    #pragma unroll
    for (int r = 0; r < 4; ++r) {
        int row = row0 + r0 + r;
        if (row < N_NODES) {
            float inv = 1.0f / cnt[row];  // cnt >= 1 always (self-loop)
            float4 o;
            o.x = fmaxf(fmaf(acc[r][0], inv, bv.x), 0.f);
            o.y = fmaxf(fmaf(acc[r][1], inv, bv.y), 0.f);
            o.z = fmaxf(fmaf(acc[r][2], inv, bv.z), 0.f);
            o.w = fmaxf(fmaf(acc[r][3], inv, bv.w), 0.f);
            *(float4*)&out[(size_t)row * CH + c0] = o;
        }
    }
}

extern "C" void kernel_launch(void* const* d_in, const int* in_sizes, int n_in,
                              void* d_out, int out_size, void* d_ws, size_t ws_size,
                              hipStream_t stream) {
    const float* x    = (const float*)d_in[0];
    const int*   ei   = (const int*)d_in[1];
    const float* Wm   = (const float*)d_in[2];
    // d_in[3] = u, d_in[4] = c : unused — softmax over a single head is 1.0
    const float* bias = (const float*)d_in[5];
    float* out = (float*)d_out;
    float* cnt = (float*)d_ws;  // N_NODES floats

    k_init<<<dim3((N_NODES * (CH / 4) + 255) / 256), dim3(256), 0, stream>>>(x, out, cnt);
    k_edges<<<dim3((N_EDGES * 32 + 255) / 256), dim3(256), 0, stream>>>(x, ei, out, cnt);
    k_gemm<<<dim3((N_NODES + ROWS - 1) / ROWS), dim3(256), 0, stream>>>(out, Wm, bias, cnt);
}

// Round 2
// 337.457 us; speedup vs baseline: 3.4380x; 3.4380x over previous
//
#include <hip/hip_runtime.h>

#define N_NODES 50000
#define N_EDGES 600000
#define CH 128
#define ROWS 32

// d_ws layout (ints):
//   [0, N)              deg
//   [N, 2N+1)           off   (CSR row offsets, exclusive prefix of deg)
//   [2N+1, 3N+1)        cur   (fill cursors)
//   [3N+1, 3N+1+E)      col   (CSR: src indices grouped by dst)
// total = 750,001 ints = 3.0 MB
#define DEG_OFF 0
#define OFF_OFF (N_NODES)
#define CUR_OFF (2 * N_NODES + 1)
#define COL_OFF (3 * N_NODES + 1)

// ---------------------------------------------------------------------------
// K0: zero the degree histogram (ws is poisoned 0xAA before every call)
// ---------------------------------------------------------------------------
__global__ __launch_bounds__(256) void k_zero(int* __restrict__ deg) {
    int i = blockIdx.x * 256 + threadIdx.x;
    if (i < N_NODES) deg[i] = 0;
}

// ---------------------------------------------------------------------------
// K1: histogram of dst — deg[dst[e]]++
// ---------------------------------------------------------------------------
__global__ __launch_bounds__(256) void k_hist(const int* __restrict__ ei,
                                              int* __restrict__ deg) {
    int e = blockIdx.x * 256 + threadIdx.x;
    if (e < N_EDGES) atomicAdd(&deg[ei[N_EDGES + e]], 1);
}

// ---------------------------------------------------------------------------
// K2: exclusive scan of deg -> off, cur (single 1024-thread block)
// ---------------------------------------------------------------------------
__global__ __launch_bounds__(1024) void k_scan(const int* __restrict__ deg,
                                               int* __restrict__ off,
                                               int* __restrict__ cur) {
    __shared__ int part[1024];
    const int t = threadIdx.x;
    const int CHUNK = (N_NODES + 1023) / 1024;  // 49
    const int base = t * CHUNK;
    int s = 0;
    for (int i = 0; i < CHUNK; ++i) {
        int n = base + i;
        if (n < N_NODES) s += deg[n];
    }
    part[t] = s;
    __syncthreads();
    for (int o = 1; o < 1024; o <<= 1) {
        int v = (t >= o) ? part[t - o] : 0;
        __syncthreads();
        part[t] += v;
        __syncthreads();
    }
    int run = (t == 0) ? 0 : part[t - 1];
    for (int i = 0; i < CHUNK; ++i) {
        int n = base + i;
        if (n < N_NODES) {
            off[n] = run;
            cur[n] = run;
            run += deg[n];
        }
    }
    if (t == 1023) off[N_NODES] = N_EDGES;
}

// ---------------------------------------------------------------------------
// K3: CSR fill — col[cur[dst]++] = src
// ---------------------------------------------------------------------------
__global__ __launch_bounds__(256) void k_fill(const int* __restrict__ ei,
                                              int* __restrict__ cur,
                                              int* __restrict__ col) {
    int e = blockIdx.x * 256 + threadIdx.x;
    if (e < N_EDGES) {
        int src = ei[e];
        int dst = ei[N_EDGES + e];
        int pos = atomicAdd(&cur[dst], 1);
        col[pos] = src;
    }
}

// ---------------------------------------------------------------------------
// K4: fused pull-aggregate + GEMM + bias + relu.
// Block = 256 threads (4 waves), 32 nodes per block.
// Phase A: wave w aggregates nodes [8w, 8w+8): acc = (x[n] + sum x[col[j]])
//          / (deg+1), lane owns channels (2*lane, 2*lane+1) -> LDS tile.
// Phase B: 32x128 @ 128x128 fp32 GEMM from LDS, thread tile 4x4.
// ---------------------------------------------------------------------------
__global__ __launch_bounds__(256) void k_agg_gemm(const float* __restrict__ x,
                                                  const int* __restrict__ off,
                                                  const int* __restrict__ col,
                                                  const float* __restrict__ Wm,
                                                  const float* __restrict__ bias,
                                                  float* __restrict__ out) {
    __shared__ float Hs[ROWS * CH];  // 16 KB
    const int t = threadIdx.x;
    const int wv = t >> 6;
    const int lane = t & 63;
    const int row0 = blockIdx.x * ROWS;

    // ---- Phase A: aggregate 8 nodes per wave ----
    for (int k = 0; k < 8; ++k) {
        const int ln = wv * 8 + k;
        const int n = row0 + ln;
        float2 acc = make_float2(0.f, 0.f);
        float inv = 1.0f;
        if (n < N_NODES) {
            acc = *(const float2*)&x[(size_t)n * CH + 2 * lane];  // self-loop
            const int rb = off[n];
            const int re = off[n + 1];
            int j = rb;
            // unroll-by-2: two col loads + two gathers in flight
            for (; j + 1 < re; j += 2) {
                int s0 = col[j];
                int s1 = col[j + 1];
                float2 a = *(const float2*)&x[(size_t)s0 * CH + 2 * lane];
                float2 b = *(const float2*)&x[(size_t)s1 * CH + 2 * lane];
                acc.x += a.x + b.x;
                acc.y += a.y + b.y;
            }
            if (j < re) {
                int s0 = col[j];
                float2 a = *(const float2*)&x[(size_t)s0 * CH + 2 * lane];
                acc.x += a.x;
                acc.y += a.y;
            }
            inv = 1.0f / (float)(re - rb + 1);
        }
        *(float2*)&Hs[ln * CH + 2 * lane] = make_float2(acc.x * inv, acc.y * inv);
    }
    __syncthreads();

    // ---- Phase B: GEMM 32x128 @ 128x128 ----
    const int cx = t & 31;  // col group: cols 4*cx..4*cx+3
    const int ry = t >> 5;  // row group: rows 4*ry..4*ry+3
    const int c0 = cx * 4;
    const int r0 = ry * 4;

    float acc[4][4] = {};
    for (int k = 0; k < CH; k += 4) {
        float4 h[4];
        #pragma unroll
        for (int r = 0; r < 4; ++r)
            h[r] = *(const float4*)&Hs[(r0 + r) * CH + k];
        #pragma unroll
        for (int kk = 0; kk < 4; ++kk) {
            float4 w = ((const float4*)(Wm + (size_t)(k + kk) * CH))[cx];
            #pragma unroll
            for (int r = 0; r < 4; ++r) {
                float hv = ((const float*)&h[r])[kk];
                acc[r][0] = fmaf(hv, w.x, acc[r][0]);
                acc[r][1] = fmaf(hv, w.y, acc[r][1]);
                acc[r][2] = fmaf(hv, w.z, acc[r][2]);
                acc[r][3] = fmaf(hv, w.w, acc[r][3]);
            }
        }
    }

    float4 bv = ((const float4*)bias)[cx];
    #pragma unroll
    for (int r = 0; r < 4; ++r) {
        int row = row0 + r0 + r;
        if (row < N_NODES) {
            float4 o;
            o.x = fmaxf(acc[r][0] + bv.x, 0.f);
            o.y = fmaxf(acc[r][1] + bv.y, 0.f);
            o.z = fmaxf(acc[r][2] + bv.z, 0.f);
            o.w = fmaxf(acc[r][3] + bv.w, 0.f);
            *(float4*)&out[(size_t)row * CH + c0] = o;
        }
    }
}

extern "C" void kernel_launch(void* const* d_in, const int* in_sizes, int n_in,
                              void* d_out, int out_size, void* d_ws, size_t ws_size,
                              hipStream_t stream) {
    const float* x    = (const float*)d_in[0];
    const int*   ei   = (const int*)d_in[1];
    const float* Wm   = (const float*)d_in[2];
    // d_in[3]=u, d_in[4]=c unused: softmax over HEADS=1 is identically 1.0
    const float* bias = (const float*)d_in[5];
    float* out = (float*)d_out;

    int* wsi = (int*)d_ws;
    int* deg = wsi + DEG_OFF;
    int* off = wsi + OFF_OFF;
    int* cur = wsi + CUR_OFF;
    int* col = wsi + COL_OFF;

    k_zero<<<dim3((N_NODES + 255) / 256), dim3(256), 0, stream>>>(deg);
    k_hist<<<dim3((N_EDGES + 255) / 256), dim3(256), 0, stream>>>(ei, deg);
    k_scan<<<dim3(1), dim3(1024), 0, stream>>>(deg, off, cur);
    k_fill<<<dim3((N_EDGES + 255) / 256), dim3(256), 0, stream>>>(ei, cur, col);
    k_agg_gemm<<<dim3((N_NODES + ROWS - 1) / ROWS), dim3(256), 0, stream>>>(
        x, off, col, Wm, bias, out);
}

// Round 3
// 219.018 us; speedup vs baseline: 5.2972x; 1.5408x over previous
//
#include <hip/hip_runtime.h>

#define N_NODES 50000
#define N_EDGES 600000
#define CH 128
#define ROWS 32
#define NB 196  // ceil(N_NODES/256) scan blocks; 196*256 = 50176

// d_ws layout (ints):
//   [0, N)                  deg
//   [N, 2N+1)               off   (CSR row offsets)
//   [2N+1, 3N+1)            cur   (fill cursors)
//   [3N+1, 3N+1+E)          col   (CSR: src grouped by dst)
//   [3N+1+E, +NB)           bsum  (per-block degree sums)
//   [3N+1+E+NB, +NB)        boff  (exclusive scan of bsum)
#define DEG_OFF 0
#define OFF_OFF (N_NODES)
#define CUR_OFF (2 * N_NODES + 1)
#define COL_OFF (3 * N_NODES + 1)
#define BSUM_OFF (3 * N_NODES + 1 + N_EDGES)
#define BOFF_OFF (BSUM_OFF + NB)

// ---------------------------------------------------------------------------
// K0: zero the degree histogram (ws is poisoned 0xAA before every call)
// ---------------------------------------------------------------------------
__global__ __launch_bounds__(256) void k_zero(int* __restrict__ deg) {
    int i = blockIdx.x * 256 + threadIdx.x;
    if (i < N_NODES) deg[i] = 0;
}

// ---------------------------------------------------------------------------
// K1: histogram of dst — deg[dst[e]]++
// ---------------------------------------------------------------------------
__global__ __launch_bounds__(256) void k_hist(const int* __restrict__ ei,
                                              int* __restrict__ deg) {
    int e = blockIdx.x * 256 + threadIdx.x;
    if (e < N_EDGES) atomicAdd(&deg[ei[N_EDGES + e]], 1);
}

// ---------------------------------------------------------------------------
// K2a: per-block sums of deg (coalesced) -> bsum[b]
// ---------------------------------------------------------------------------
__global__ __launch_bounds__(256) void k_scan1(const int* __restrict__ deg,
                                               int* __restrict__ bsum) {
    __shared__ int red[256];
    int t = threadIdx.x;
    int i = blockIdx.x * 256 + t;
    red[t] = (i < N_NODES) ? deg[i] : 0;
    __syncthreads();
    for (int o = 128; o > 0; o >>= 1) {
        if (t < o) red[t] += red[t + o];
        __syncthreads();
    }
    if (t == 0) bsum[blockIdx.x] = red[0];
}

// ---------------------------------------------------------------------------
// K2b: exclusive scan of NB block sums -> boff (single small block)
// ---------------------------------------------------------------------------
__global__ __launch_bounds__(256) void k_scan2(const int* __restrict__ bsum,
                                               int* __restrict__ boff) {
    __shared__ int part[256];
    int t = threadIdx.x;
    part[t] = (t < NB) ? bsum[t] : 0;
    __syncthreads();
    for (int o = 1; o < 256; o <<= 1) {
        int v = (t >= o) ? part[t - o] : 0;
        __syncthreads();
        part[t] += v;
        __syncthreads();
    }
    if (t < NB) boff[t] = (t == 0) ? 0 : part[t - 1];
}

// ---------------------------------------------------------------------------
// K2c: block-local exclusive scan + boff -> off, cur;  off[N] = E
// ---------------------------------------------------------------------------
__global__ __launch_bounds__(256) void k_scan3(const int* __restrict__ deg,
                                               const int* __restrict__ boff,
                                               int* __restrict__ off,
                                               int* __restrict__ cur) {
    __shared__ int part[256];
    int t = threadIdx.x;
    int i = blockIdx.x * 256 + t;
    int d = (i < N_NODES) ? deg[i] : 0;
    part[t] = d;
    __syncthreads();
    for (int o = 1; o < 256; o <<= 1) {
        int v = (t >= o) ? part[t - o] : 0;
        __syncthreads();
        part[t] += v;
        __syncthreads();
    }
    if (i < N_NODES) {
        int excl = boff[blockIdx.x] + part[t] - d;  // inclusive - self
        off[i] = excl;
        cur[i] = excl;
    }
    if (i == N_NODES) off[N_NODES] = N_EDGES;
}

// ---------------------------------------------------------------------------
// K3: CSR fill — col[cur[dst]++] = src
// ---------------------------------------------------------------------------
__global__ __launch_bounds__(256) void k_fill(const int* __restrict__ ei,
                                              int* __restrict__ cur,
                                              int* __restrict__ col) {
    int e = blockIdx.x * 256 + threadIdx.x;
    if (e < N_EDGES) {
        int src = ei[e];
        int dst = ei[N_EDGES + e];
        int pos = atomicAdd(&cur[dst], 1);
        col[pos] = src;
    }
}

// ---------------------------------------------------------------------------
// K4: fused pull-aggregate + GEMM + bias + relu.
// Block = 256 threads (4 waves), 32 nodes per block.
// Phase A: wave wv handles nodes [8wv, 8wv+8) as 4 half-wave pairs:
//          half-wave (32 lanes, float4 each = 128 ch) pulls one node's
//          neighbor rows; unroll-2 -> 4 independent 512B gathers in flight
//          per wave. Mean = (x[n] + sum x[col]) / (deg+1) -> LDS.
// Phase B: 32x128 @ 128x128 fp32 GEMM from LDS, thread tile 4x4.
// ---------------------------------------------------------------------------
__global__ __launch_bounds__(256) void k_agg_gemm(const float* __restrict__ x,
                                                  const int* __restrict__ off,
                                                  const int* __restrict__ col,
                                                  const float* __restrict__ Wm,
                                                  const float* __restrict__ bias,
                                                  float* __restrict__ out) {
    __shared__ float Hs[ROWS * CH];  // 16 KB
    const int t = threadIdx.x;
    const int wv = t >> 6;
    const int lane = t & 63;
    const int half = lane >> 5;  // which node of the pair
    const int l32 = lane & 31;   // float4 index within the 128-ch row
    const int row0 = blockIdx.x * ROWS;

    // ---- Phase A ----
    for (int k = 0; k < 8; k += 2) {
        const int ln = wv * 8 + k + half;
        const int n = row0 + ln;
        float4 acc = make_float4(0.f, 0.f, 0.f, 0.f);
        float inv = 1.0f;
        if (n < N_NODES) {
            acc = ((const float4*)(x + (size_t)n * CH))[l32];  // self-loop
            const int rb = off[n];
            const int re = off[n + 1];
            int j = rb;
            for (; j + 1 < re; j += 2) {
                int s0 = col[j];
                int s1 = col[j + 1];
                float4 a = ((const float4*)(x + (size_t)s0 * CH))[l32];
                float4 b = ((const float4*)(x + (size_t)s1 * CH))[l32];
                acc.x += a.x + b.x;
                acc.y += a.y + b.y;
                acc.z += a.z + b.z;
                acc.w += a.w + b.w;
            }
            if (j < re) {
                int s0 = col[j];
                float4 a = ((const float4*)(x + (size_t)s0 * CH))[l32];
                acc.x += a.x;
                acc.y += a.y;
                acc.z += a.z;
                acc.w += a.w;
            }
            inv = 1.0f / (float)(re - rb + 1);
        }
        float4 o = make_float4(acc.x * inv, acc.y * inv, acc.z * inv, acc.w * inv);
        ((float4*)(Hs + ln * CH))[l32] = o;
    }
    __syncthreads();

    // ---- Phase B ----
    const int cx = t & 31;  // col group: cols 4*cx..4*cx+3
    const int ry = t >> 5;  // row group: rows 4*ry..4*ry+3
    const int c0 = cx * 4;
    const int r0 = ry * 4;

    float acc[4][4] = {};
    for (int k = 0; k < CH; k += 4) {
        float4 h[4];
        #pragma unroll
        for (int r = 0; r < 4; ++r)
            h[r] = *(const float4*)&Hs[(r0 + r) * CH + k];
        #pragma unroll
        for (int kk = 0; kk < 4; ++kk) {
            float4 w = ((const float4*)(Wm + (size_t)(k + kk) * CH))[cx];
            #pragma unroll
            for (int r = 0; r < 4; ++r) {
                float hv = ((const float*)&h[r])[kk];
                acc[r][0] = fmaf(hv, w.x, acc[r][0]);
                acc[r][1] = fmaf(hv, w.y, acc[r][1]);
                acc[r][2] = fmaf(hv, w.z, acc[r][2]);
                acc[r][3] = fmaf(hv, w.w, acc[r][3]);
            }
        }
    }

    float4 bv = ((const float4*)bias)[cx];
    #pragma unroll
    for (int r = 0; r < 4; ++r) {
        int row = row0 + r0 + r;
        if (row < N_NODES) {
            float4 o;
            o.x = fmaxf(acc[r][0] + bv.x, 0.f);
            o.y = fmaxf(acc[r][1] + bv.y, 0.f);
            o.z = fmaxf(acc[r][2] + bv.z, 0.f);
            o.w = fmaxf(acc[r][3] + bv.w, 0.f);
            *(float4*)&out[(size_t)row * CH + c0] = o;
        }
    }
}

extern "C" void kernel_launch(void* const* d_in, const int* in_sizes, int n_in,
                              void* d_out, int out_size, void* d_ws, size_t ws_size,
                              hipStream_t stream) {
    const float* x    = (const float*)d_in[0];
    const int*   ei   = (const int*)d_in[1];
    const float* Wm   = (const float*)d_in[2];
    // d_in[3]=u, d_in[4]=c unused: softmax over HEADS=1 is identically 1.0
    const float* bias = (const float*)d_in[5];
    float* out = (float*)d_out;

    int* wsi  = (int*)d_ws;
    int* deg  = wsi + DEG_OFF;
    int* off  = wsi + OFF_OFF;
    int* cur  = wsi + CUR_OFF;
    int* col  = wsi + COL_OFF;
    int* bsum = wsi + BSUM_OFF;
    int* boff = wsi + BOFF_OFF;

    k_zero<<<dim3((N_NODES + 255) / 256), dim3(256), 0, stream>>>(deg);
    k_hist<<<dim3((N_EDGES + 255) / 256), dim3(256), 0, stream>>>(ei, deg);
    k_scan1<<<dim3(NB), dim3(256), 0, stream>>>(deg, bsum);
    k_scan2<<<dim3(1), dim3(256), 0, stream>>>(bsum, boff);
    k_scan3<<<dim3(NB), dim3(256), 0, stream>>>(deg, boff, off, cur);
    k_fill<<<dim3((N_EDGES + 255) / 256), dim3(256), 0, stream>>>(ei, cur, col);
    k_agg_gemm<<<dim3((N_NODES + ROWS - 1) / ROWS), dim3(256), 0, stream>>>(
        x, off, col, Wm, bias, out);
}

// Round 4
// 197.146 us; speedup vs baseline: 5.8849x; 1.1109x over previous
//
#include <hip/hip_runtime.h>

#define N_NODES 50000
#define N_EDGES 600000
#define CH 128
#define ROWS 32
#define NB 196  // ceil(N_NODES/256)

// d_ws layout (ints), built host-side with PAD decided from ws_size:
//   deg_p  [0, N*PAD)        padded degree counters (1 per PAD ints)
//   off    [N*PAD, +N+1)     CSR row offsets
//   rank   [.., +E)          per-edge slot within its dst row
//   col    [.., +E)          CSR adjacency (src grouped by dst)
//   bsum   [.., +NB)
//   boff   [.., +NB)

// ---------------------------------------------------------------------------
__global__ __launch_bounds__(256) void k_zero(int* __restrict__ deg, int n) {
    int i = blockIdx.x * 256 + threadIdx.x;
    int4 z = make_int4(0, 0, 0, 0);
    if (i * 4 < n) ((int4*)deg)[i] = z;  // n is a multiple of 4
}

// ---------------------------------------------------------------------------
// hist + rank capture: rank[e] = deg[dst[e]]++  (padded counters)
// 4 edges per thread, int4 I/O.
// ---------------------------------------------------------------------------
__global__ __launch_bounds__(256) void k_hist(const int* __restrict__ ei,
                                              int* __restrict__ deg,
                                              int* __restrict__ rank,
                                              int pad) {
    int idx = blockIdx.x * 256 + threadIdx.x;  // int4 index
    if (idx * 4 >= N_EDGES) return;
    int4 d = ((const int4*)(ei + N_EDGES))[idx];
    int4 r;
    r.x = atomicAdd(&deg[d.x * pad], 1);
    r.y = atomicAdd(&deg[d.y * pad], 1);
    r.z = atomicAdd(&deg[d.z * pad], 1);
    r.w = atomicAdd(&deg[d.w * pad], 1);
    ((int4*)rank)[idx] = r;
}

// ---------------------------------------------------------------------------
__global__ __launch_bounds__(256) void k_scan1(const int* __restrict__ deg,
                                               int* __restrict__ bsum, int pad) {
    __shared__ int red[256];
    int t = threadIdx.x;
    int i = blockIdx.x * 256 + t;
    red[t] = (i < N_NODES) ? deg[i * pad] : 0;
    __syncthreads();
    for (int o = 128; o > 0; o >>= 1) {
        if (t < o) red[t] += red[t + o];
        __syncthreads();
    }
    if (t == 0) bsum[blockIdx.x] = red[0];
}

__global__ __launch_bounds__(256) void k_scan2(const int* __restrict__ bsum,
                                               int* __restrict__ boff) {
    __shared__ int part[256];
    int t = threadIdx.x;
    part[t] = (t < NB) ? bsum[t] : 0;
    __syncthreads();
    for (int o = 1; o < 256; o <<= 1) {
        int v = (t >= o) ? part[t - o] : 0;
        __syncthreads();
        part[t] += v;
        __syncthreads();
    }
    if (t < NB) boff[t] = (t == 0) ? 0 : part[t - 1];
}

__global__ __launch_bounds__(256) void k_scan3(const int* __restrict__ deg,
                                               const int* __restrict__ boff,
                                               int* __restrict__ off, int pad) {
    __shared__ int part[256];
    int t = threadIdx.x;
    int i = blockIdx.x * 256 + t;
    int d = (i < N_NODES) ? deg[i * pad] : 0;
    part[t] = d;
    __syncthreads();
    for (int o = 1; o < 256; o <<= 1) {
        int v = (t >= o) ? part[t - o] : 0;
        __syncthreads();
        part[t] += v;
        __syncthreads();
    }
    if (i < N_NODES) off[i] = boff[blockIdx.x] + part[t] - d;
    if (i == N_NODES - 1 && blockIdx.x == NB - 1) off[N_NODES] = N_EDGES;
}

// ---------------------------------------------------------------------------
// CSR fill, atomic-free: col[off[dst] + rank[e]] = src
// ---------------------------------------------------------------------------
__global__ __launch_bounds__(256) void k_fill(const int* __restrict__ ei,
                                              const int* __restrict__ off,
                                              const int* __restrict__ rank,
                                              int* __restrict__ col) {
    int idx = blockIdx.x * 256 + threadIdx.x;  // int4 index
    if (idx * 4 >= N_EDGES) return;
    int4 s = ((const int4*)ei)[idx];
    int4 d = ((const int4*)(ei + N_EDGES))[idx];
    int4 r = ((const int4*)rank)[idx];
    col[off[d.x] + r.x] = s.x;
    col[off[d.y] + r.y] = s.y;
    col[off[d.z] + r.z] = s.z;
    col[off[d.w] + r.w] = s.w;
}

// ---------------------------------------------------------------------------
// K4: fused pull-aggregate + GEMM + bias + relu (unchanged structure,
// gather loop unrolled x4 for 8 concurrent 512B row-reads per wave).
// ---------------------------------------------------------------------------
__global__ __launch_bounds__(256) void k_agg_gemm(const float* __restrict__ x,
                                                  const int* __restrict__ off,
                                                  const int* __restrict__ col,
                                                  const float* __restrict__ Wm,
                                                  const float* __restrict__ bias,
                                                  float* __restrict__ out) {
    __shared__ float Hs[ROWS * CH];  // 16 KB
    const int t = threadIdx.x;
    const int wv = t >> 6;
    const int lane = t & 63;
    const int half = lane >> 5;
    const int l32 = lane & 31;
    const int row0 = blockIdx.x * ROWS;

    // ---- Phase A ----
    for (int k = 0; k < 8; k += 2) {
        const int ln = wv * 8 + k + half;
        const int n = row0 + ln;
        float4 acc = make_float4(0.f, 0.f, 0.f, 0.f);
        float inv = 1.0f;
        if (n < N_NODES) {
            acc = ((const float4*)(x + (size_t)n * CH))[l32];  // self-loop
            const int rb = off[n];
            const int re = off[n + 1];
            int j = rb;
            for (; j + 3 < re; j += 4) {
                int s0 = col[j], s1 = col[j + 1], s2 = col[j + 2], s3 = col[j + 3];
                float4 a = ((const float4*)(x + (size_t)s0 * CH))[l32];
                float4 b = ((const float4*)(x + (size_t)s1 * CH))[l32];
                float4 c = ((const float4*)(x + (size_t)s2 * CH))[l32];
                float4 d = ((const float4*)(x + (size_t)s3 * CH))[l32];
                acc.x += (a.x + b.x) + (c.x + d.x);
                acc.y += (a.y + b.y) + (c.y + d.y);
                acc.z += (a.z + b.z) + (c.z + d.z);
                acc.w += (a.w + b.w) + (c.w + d.w);
            }
            for (; j < re; ++j) {
                int s0 = col[j];
                float4 a = ((const float4*)(x + (size_t)s0 * CH))[l32];
                acc.x += a.x; acc.y += a.y; acc.z += a.z; acc.w += a.w;
            }
            inv = 1.0f / (float)(re - rb + 1);
        }
        ((float4*)(Hs + ln * CH))[l32] =
            make_float4(acc.x * inv, acc.y * inv, acc.z * inv, acc.w * inv);
    }
    __syncthreads();

    // ---- Phase B: 32x128 @ 128x128 fp32 GEMM ----
    const int cx = t & 31;
    const int ry = t >> 5;
    const int c0 = cx * 4;
    const int r0 = ry * 4;

    float acc[4][4] = {};
    for (int k = 0; k < CH; k += 4) {
        float4 h[4];
        #pragma unroll
        for (int r = 0; r < 4; ++r)
            h[r] = *(const float4*)&Hs[(r0 + r) * CH + k];
        #pragma unroll
        for (int kk = 0; kk < 4; ++kk) {
            float4 w = ((const float4*)(Wm + (size_t)(k + kk) * CH))[cx];
            #pragma unroll
            for (int r = 0; r < 4; ++r) {
                float hv = ((const float*)&h[r])[kk];
                acc[r][0] = fmaf(hv, w.x, acc[r][0]);
                acc[r][1] = fmaf(hv, w.y, acc[r][1]);
                acc[r][2] = fmaf(hv, w.z, acc[r][2]);
                acc[r][3] = fmaf(hv, w.w, acc[r][3]);
            }
        }
    }

    float4 bv = ((const float4*)bias)[cx];
    #pragma unroll
    for (int r = 0; r < 4; ++r) {
        int row = row0 + r0 + r;
        if (row < N_NODES) {
            float4 o;
            o.x = fmaxf(acc[r][0] + bv.x, 0.f);
            o.y = fmaxf(acc[r][1] + bv.y, 0.f);
            o.z = fmaxf(acc[r][2] + bv.z, 0.f);
            o.w = fmaxf(acc[r][3] + bv.w, 0.f);
            *(float4*)&out[(size_t)row * CH + c0] = o;
        }
    }
}

extern "C" void kernel_launch(void* const* d_in, const int* in_sizes, int n_in,
                              void* d_out, int out_size, void* d_ws, size_t ws_size,
                              hipStream_t stream) {
    const float* x    = (const float*)d_in[0];
    const int*   ei   = (const int*)d_in[1];
    const float* Wm   = (const float*)d_in[2];
    // d_in[3]=u, d_in[4]=c unused: softmax over HEADS=1 is identically 1.0
    const float* bias = (const float*)d_in[5];
    float* out = (float*)d_out;

    // pick counter padding from available scratch (deterministic per harness)
    const size_t fixed = (size_t)(N_NODES + 1 + 2 * N_EDGES + 2 * NB) * 4;
    int pad = 1;
    if (ws_size >= fixed + (size_t)N_NODES * 32 * 4) pad = 32;       // 1 cnt / 128B line
    else if (ws_size >= fixed + (size_t)N_NODES * 16 * 4) pad = 16;  // 2 cnt / line
    const int degN = ((N_NODES * pad + 3) / 4) * 4;

    int* wsi  = (int*)d_ws;
    int* deg  = wsi;
    int* off  = deg + degN;
    int* rank = off + N_NODES + 1;
    int* col  = rank + N_EDGES;
    int* bsum = col + N_EDGES;
    int* boff = bsum + NB;

    k_zero<<<dim3((degN / 4 + 255) / 256), dim3(256), 0, stream>>>(deg, degN);
    k_hist<<<dim3((N_EDGES / 4 + 255) / 256), dim3(256), 0, stream>>>(ei, deg, rank, pad);
    k_scan1<<<dim3(NB), dim3(256), 0, stream>>>(deg, bsum, pad);
    k_scan2<<<dim3(1), dim3(256), 0, stream>>>(bsum, boff);
    k_scan3<<<dim3(NB), dim3(256), 0, stream>>>(deg, boff, off, pad);
    k_fill<<<dim3((N_EDGES / 4 + 255) / 256), dim3(256), 0, stream>>>(ei, off, rank, col);
    k_agg_gemm<<<dim3((N_NODES + ROWS - 1) / ROWS), dim3(256), 0, stream>>>(
        x, off, col, Wm, bias, out);
}

// Round 5
// 187.935 us; speedup vs baseline: 6.1733x; 1.0490x over previous
//
#include <hip/hip_runtime.h>

#define N_NODES 50000
#define N_EDGES 600000
#define CH 128
#define ROWS 32
#define NB 196  // ceil(N_NODES/256)

// ---------------------------------------------------------------------------
// fp32 -> bf16 (RNE) pack of x into workspace
// ---------------------------------------------------------------------------
__device__ inline unsigned short f2bf(float f) {
    unsigned int b = __float_as_uint(f);
    unsigned int r = b + 0x7fffu + ((b >> 16) & 1u);
    return (unsigned short)(r >> 16);
}

__global__ __launch_bounds__(256) void k_cvt(const float* __restrict__ x,
                                             unsigned short* __restrict__ xh) {
    int i = blockIdx.x * 256 + threadIdx.x;  // float4 index
    if (i * 4 < N_NODES * CH) {
        float4 v = ((const float4*)x)[i];
        ushort4 o;
        o.x = f2bf(v.x); o.y = f2bf(v.y); o.z = f2bf(v.z); o.w = f2bf(v.w);
        ((ushort4*)xh)[i] = o;
    }
}

// ---------------------------------------------------------------------------
// hist + rank capture: rank[e] = deg[dst[e]]++  (padded counters)
// ---------------------------------------------------------------------------
__global__ __launch_bounds__(256) void k_hist(const int* __restrict__ ei,
                                              int* __restrict__ deg,
                                              int* __restrict__ rank,
                                              int pad) {
    int idx = blockIdx.x * 256 + threadIdx.x;  // int4 index
    if (idx * 4 >= N_EDGES) return;
    int4 d = ((const int4*)(ei + N_EDGES))[idx];
    int4 r;
    r.x = atomicAdd(&deg[d.x * pad], 1);
    r.y = atomicAdd(&deg[d.y * pad], 1);
    r.z = atomicAdd(&deg[d.z * pad], 1);
    r.w = atomicAdd(&deg[d.w * pad], 1);
    ((int4*)rank)[idx] = r;
}

// ---------------------------------------------------------------------------
__global__ __launch_bounds__(256) void k_scan1(const int* __restrict__ deg,
                                               int* __restrict__ bsum, int pad) {
    __shared__ int red[256];
    int t = threadIdx.x;
    int i = blockIdx.x * 256 + t;
    red[t] = (i < N_NODES) ? deg[i * pad] : 0;
    __syncthreads();
    for (int o = 128; o > 0; o >>= 1) {
        if (t < o) red[t] += red[t + o];
        __syncthreads();
    }
    if (t == 0) bsum[blockIdx.x] = red[0];
}

__global__ __launch_bounds__(256) void k_scan2(const int* __restrict__ bsum,
                                               int* __restrict__ boff) {
    __shared__ int part[256];
    int t = threadIdx.x;
    part[t] = (t < NB) ? bsum[t] : 0;
    __syncthreads();
    for (int o = 1; o < 256; o <<= 1) {
        int v = (t >= o) ? part[t - o] : 0;
        __syncthreads();
        part[t] += v;
        __syncthreads();
    }
    if (t < NB) boff[t] = (t == 0) ? 0 : part[t - 1];
}

__global__ __launch_bounds__(256) void k_scan3(const int* __restrict__ deg,
                                               const int* __restrict__ boff,
                                               int* __restrict__ off, int pad) {
    __shared__ int part[256];
    int t = threadIdx.x;
    int i = blockIdx.x * 256 + t;
    int d = (i < N_NODES) ? deg[i * pad] : 0;
    part[t] = d;
    __syncthreads();
    for (int o = 1; o < 256; o <<= 1) {
        int v = (t >= o) ? part[t - o] : 0;
        __syncthreads();
        part[t] += v;
        __syncthreads();
    }
    if (i < N_NODES) off[i] = boff[blockIdx.x] + part[t] - d;
    if (i == N_NODES - 1 && blockIdx.x == NB - 1) off[N_NODES] = N_EDGES;
}

// ---------------------------------------------------------------------------
// CSR fill, atomic-free: col[off[dst] + rank[e]] = src
// ---------------------------------------------------------------------------
__global__ __launch_bounds__(256) void k_fill(const int* __restrict__ ei,
                                              const int* __restrict__ off,
                                              const int* __restrict__ rank,
                                              int* __restrict__ col) {
    int idx = blockIdx.x * 256 + threadIdx.x;  // int4 index
    if (idx * 4 >= N_EDGES) return;
    int4 s = ((const int4*)ei)[idx];
    int4 d = ((const int4*)(ei + N_EDGES))[idx];
    int4 r = ((const int4*)rank)[idx];
    col[off[d.x] + r.x] = s.x;
    col[off[d.y] + r.y] = s.y;
    col[off[d.z] + r.z] = s.z;
    col[off[d.w] + r.w] = s.w;
}

// ---------------------------------------------------------------------------
// Fused pull-aggregate (bf16 gather) + fp32 GEMM + bias + relu.
// Lane l32 owns channels 4*l32..4*l32+3. Self row read fp32 (exact);
// neighbor rows gathered from bf16 copy (256B/row, 2 lines) and widened.
// ---------------------------------------------------------------------------
__device__ inline float4 bf4_widen(ushort4 u) {
    float4 f;
    f.x = __uint_as_float((unsigned int)u.x << 16);
    f.y = __uint_as_float((unsigned int)u.y << 16);
    f.z = __uint_as_float((unsigned int)u.z << 16);
    f.w = __uint_as_float((unsigned int)u.w << 16);
    return f;
}

__global__ __launch_bounds__(256) void k_agg_gemm_bf(
    const float* __restrict__ x, const unsigned short* __restrict__ xh,
    const int* __restrict__ off, const int* __restrict__ col,
    const float* __restrict__ Wm, const float* __restrict__ bias,
    float* __restrict__ out) {
    __shared__ float Hs[ROWS * CH];  // 16 KB
    const int t = threadIdx.x;
    const int wv = t >> 6;
    const int lane = t & 63;
    const int half = lane >> 5;
    const int l32 = lane & 31;
    const int row0 = blockIdx.x * ROWS;

    // ---- Phase A ----
    for (int k = 0; k < 8; k += 2) {
        const int ln = wv * 8 + k + half;
        const int n = row0 + ln;
        float4 acc = make_float4(0.f, 0.f, 0.f, 0.f);
        float inv = 1.0f;
        if (n < N_NODES) {
            acc = ((const float4*)(x + (size_t)n * CH))[l32];  // self-loop, fp32
            const int rb = off[n];
            const int re = off[n + 1];
            int j = rb;
            for (; j + 3 < re; j += 4) {
                int s0 = col[j], s1 = col[j + 1], s2 = col[j + 2], s3 = col[j + 3];
                ushort4 ua = ((const ushort4*)(xh + (size_t)s0 * CH))[l32];
                ushort4 ub = ((const ushort4*)(xh + (size_t)s1 * CH))[l32];
                ushort4 uc = ((const ushort4*)(xh + (size_t)s2 * CH))[l32];
                ushort4 ud = ((const ushort4*)(xh + (size_t)s3 * CH))[l32];
                float4 a = bf4_widen(ua), b = bf4_widen(ub);
                float4 c = bf4_widen(uc), d = bf4_widen(ud);
                acc.x += (a.x + b.x) + (c.x + d.x);
                acc.y += (a.y + b.y) + (c.y + d.y);
                acc.z += (a.z + b.z) + (c.z + d.z);
                acc.w += (a.w + b.w) + (c.w + d.w);
            }
            for (; j < re; ++j) {
                float4 a = bf4_widen(((const ushort4*)(xh + (size_t)col[j] * CH))[l32]);
                acc.x += a.x; acc.y += a.y; acc.z += a.z; acc.w += a.w;
            }
            inv = 1.0f / (float)(re - rb + 1);
        }
        ((float4*)(Hs + ln * CH))[l32] =
            make_float4(acc.x * inv, acc.y * inv, acc.z * inv, acc.w * inv);
    }
    __syncthreads();

    // ---- Phase B: 32x128 @ 128x128 fp32 GEMM ----
    const int cx = t & 31;
    const int ry = t >> 5;
    const int c0 = cx * 4;
    const int r0 = ry * 4;

    float acc[4][4] = {};
    for (int k = 0; k < CH; k += 4) {
        float4 h[4];
        #pragma unroll
        for (int r = 0; r < 4; ++r)
            h[r] = *(const float4*)&Hs[(r0 + r) * CH + k];
        #pragma unroll
        for (int kk = 0; kk < 4; ++kk) {
            float4 w = ((const float4*)(Wm + (size_t)(k + kk) * CH))[cx];
            #pragma unroll
            for (int r = 0; r < 4; ++r) {
                float hv = ((const float*)&h[r])[kk];
                acc[r][0] = fmaf(hv, w.x, acc[r][0]);
                acc[r][1] = fmaf(hv, w.y, acc[r][1]);
                acc[r][2] = fmaf(hv, w.z, acc[r][2]);
                acc[r][3] = fmaf(hv, w.w, acc[r][3]);
            }
        }
    }

    float4 bv = ((const float4*)bias)[cx];
    #pragma unroll
    for (int r = 0; r < 4; ++r) {
        int row = row0 + r0 + r;
        if (row < N_NODES) {
            float4 o;
            o.x = fmaxf(acc[r][0] + bv.x, 0.f);
            o.y = fmaxf(acc[r][1] + bv.y, 0.f);
            o.z = fmaxf(acc[r][2] + bv.z, 0.f);
            o.w = fmaxf(acc[r][3] + bv.w, 0.f);
            *(float4*)&out[(size_t)row * CH + c0] = o;
        }
    }
}

// fp32 fallback gather (only used if ws can't hold the bf16 copy)
__global__ __launch_bounds__(256) void k_agg_gemm_f32(
    const float* __restrict__ x, const int* __restrict__ off,
    const int* __restrict__ col, const float* __restrict__ Wm,
    const float* __restrict__ bias, float* __restrict__ out) {
    __shared__ float Hs[ROWS * CH];
    const int t = threadIdx.x;
    const int wv = t >> 6;
    const int lane = t & 63;
    const int half = lane >> 5;
    const int l32 = lane & 31;
    const int row0 = blockIdx.x * ROWS;

    for (int k = 0; k < 8; k += 2) {
        const int ln = wv * 8 + k + half;
        const int n = row0 + ln;
        float4 acc = make_float4(0.f, 0.f, 0.f, 0.f);
        float inv = 1.0f;
        if (n < N_NODES) {
            acc = ((const float4*)(x + (size_t)n * CH))[l32];
            const int rb = off[n];
            const int re = off[n + 1];
            int j = rb;
            for (; j + 1 < re; j += 2) {
                int s0 = col[j], s1 = col[j + 1];
                float4 a = ((const float4*)(x + (size_t)s0 * CH))[l32];
                float4 b = ((const float4*)(x + (size_t)s1 * CH))[l32];
                acc.x += a.x + b.x; acc.y += a.y + b.y;
                acc.z += a.z + b.z; acc.w += a.w + b.w;
            }
            if (j < re) {
                float4 a = ((const float4*)(x + (size_t)col[j] * CH))[l32];
                acc.x += a.x; acc.y += a.y; acc.z += a.z; acc.w += a.w;
            }
            inv = 1.0f / (float)(re - rb + 1);
        }
        ((float4*)(Hs + ln * CH))[l32] =
            make_float4(acc.x * inv, acc.y * inv, acc.z * inv, acc.w * inv);
    }
    __syncthreads();

    const int cx = t & 31;
    const int ry = t >> 5;
    const int c0 = cx * 4;
    const int r0 = ry * 4;
    float acc[4][4] = {};
    for (int k = 0; k < CH; k += 4) {
        float4 h[4];
        #pragma unroll
        for (int r = 0; r < 4; ++r)
            h[r] = *(const float4*)&Hs[(r0 + r) * CH + k];
        #pragma unroll
        for (int kk = 0; kk < 4; ++kk) {
            float4 w = ((const float4*)(Wm + (size_t)(k + kk) * CH))[cx];
            #pragma unroll
            for (int r = 0; r < 4; ++r) {
                float hv = ((const float*)&h[r])[kk];
                acc[r][0] = fmaf(hv, w.x, acc[r][0]);
                acc[r][1] = fmaf(hv, w.y, acc[r][1]);
                acc[r][2] = fmaf(hv, w.z, acc[r][2]);
                acc[r][3] = fmaf(hv, w.w, acc[r][3]);
            }
        }
    }
    float4 bv = ((const float4*)bias)[cx];
    #pragma unroll
    for (int r = 0; r < 4; ++r) {
        int row = row0 + r0 + r;
        if (row < N_NODES) {
            float4 o;
            o.x = fmaxf(acc[r][0] + bv.x, 0.f);
            o.y = fmaxf(acc[r][1] + bv.y, 0.f);
            o.z = fmaxf(acc[r][2] + bv.z, 0.f);
            o.w = fmaxf(acc[r][3] + bv.w, 0.f);
            *(float4*)&out[(size_t)row * CH + c0] = o;
        }
    }
}

extern "C" void kernel_launch(void* const* d_in, const int* in_sizes, int n_in,
                              void* d_out, int out_size, void* d_ws, size_t ws_size,
                              hipStream_t stream) {
    const float* x    = (const float*)d_in[0];
    const int*   ei   = (const int*)d_in[1];
    const float* Wm   = (const float*)d_in[2];
    // d_in[3]=u, d_in[4]=c unused: softmax over HEADS=1 is identically 1.0
    const float* bias = (const float*)d_in[5];
    float* out = (float*)d_out;

    const size_t xh_bytes    = (size_t)N_NODES * CH * 2;  // 12.8 MB
    const size_t fixed_ints  = (size_t)(N_NODES + 1 + 2 * N_EDGES + 2 * NB);
    const size_t fixed_bytes = fixed_ints * 4;

    // decide bf16 copy + counter padding from available scratch
    int use_bf16 = (ws_size >= xh_bytes + fixed_bytes + (size_t)N_NODES * 4);
    size_t base = use_bf16 ? xh_bytes : 0;
    int pad = 1;
    if (ws_size >= base + fixed_bytes + (size_t)N_NODES * 32 * 4) pad = 32;
    else if (ws_size >= base + fixed_bytes + (size_t)N_NODES * 16 * 4) pad = 16;
    const int degN = ((N_NODES * pad + 3) / 4) * 4;

    unsigned short* xh = (unsigned short*)d_ws;
    int* wsi  = (int*)((char*)d_ws + base);
    int* deg  = wsi;
    int* off  = deg + degN;
    int* rank = off + N_NODES + 1;
    int* col  = rank + N_EDGES;
    int* bsum = col + N_EDGES;
    int* boff = bsum + NB;

    hipMemsetAsync(deg, 0, (size_t)degN * 4, stream);
    if (use_bf16)
        k_cvt<<<dim3((N_NODES * CH / 4 + 255) / 256), dim3(256), 0, stream>>>(x, xh);
    k_hist<<<dim3((N_EDGES / 4 + 255) / 256), dim3(256), 0, stream>>>(ei, deg, rank, pad);
    k_scan1<<<dim3(NB), dim3(256), 0, stream>>>(deg, bsum, pad);
    k_scan2<<<dim3(1), dim3(256), 0, stream>>>(bsum, boff);
    k_scan3<<<dim3(NB), dim3(256), 0, stream>>>(deg, boff, off, pad);
    k_fill<<<dim3((N_EDGES / 4 + 255) / 256), dim3(256), 0, stream>>>(ei, off, rank, col);
    if (use_bf16)
        k_agg_gemm_bf<<<dim3((N_NODES + ROWS - 1) / ROWS), dim3(256), 0, stream>>>(
            x, xh, off, col, Wm, bias, out);
    else
        k_agg_gemm_f32<<<dim3((N_NODES + ROWS - 1) / ROWS), dim3(256), 0, stream>>>(
            x, off, col, Wm, bias, out);
}

// Round 6
// 178.678 us; speedup vs baseline: 6.4931x; 1.0518x over previous
//
#include <hip/hip_runtime.h>

#define N_NODES 50000
#define N_EDGES 600000
#define CH 128
#define ROWS 32
#define NB 196  // ceil(N_NODES/256)

typedef __attribute__((ext_vector_type(8))) short bf16x8;
typedef __attribute__((ext_vector_type(4))) float f32x4;

// fp32 -> bf16 RNE
__device__ inline unsigned int f2bf(float f) {
    unsigned int b = __float_as_uint(f);
    unsigned int r = b + 0x7fffu + ((b >> 16) & 1u);
    return r >> 16;
}

// ---------------------------------------------------------------------------
// prep: zero deg, x -> bf16 copy, W -> bf16 transposed copy (Wt[n][k]=W[k][n])
// ---------------------------------------------------------------------------
__global__ __launch_bounds__(256) void k_prep(const float* __restrict__ x,
                                              const float* __restrict__ Wm,
                                              unsigned short* __restrict__ xh,
                                              unsigned short* __restrict__ Wt,
                                              int* __restrict__ deg, int degN) {
    int i = blockIdx.x * 256 + threadIdx.x;
    const int NX4 = N_NODES * CH / 4;  // 1.6M float4
    if (i < NX4) {
        float4 v = ((const float4*)x)[i];
        ushort4 o;
        o.x = (unsigned short)f2bf(v.x);
        o.y = (unsigned short)f2bf(v.y);
        o.z = (unsigned short)f2bf(v.z);
        o.w = (unsigned short)f2bf(v.w);
        ((ushort4*)xh)[i] = o;
    }
    if (i < degN / 4) ((int4*)deg)[i] = make_int4(0, 0, 0, 0);
    if (i < CH * CH) {
        int n = i >> 7, k = i & 127;
        Wt[n * CH + k] = (unsigned short)f2bf(Wm[k * CH + n]);
    }
}

// ---------------------------------------------------------------------------
// hist + rank: rank[e] = deg[dst[e]*pad]++
// ---------------------------------------------------------------------------
__global__ __launch_bounds__(256) void k_hist(const int* __restrict__ ei,
                                              int* __restrict__ deg,
                                              int* __restrict__ rank, int pad) {
    int idx = blockIdx.x * 256 + threadIdx.x;
    if (idx * 4 >= N_EDGES) return;
    int4 d = ((const int4*)(ei + N_EDGES))[idx];
    int4 r;
    r.x = atomicAdd(&deg[d.x * pad], 1);
    r.y = atomicAdd(&deg[d.y * pad], 1);
    r.z = atomicAdd(&deg[d.z * pad], 1);
    r.w = atomicAdd(&deg[d.w * pad], 1);
    ((int4*)rank)[idx] = r;
}

// ---------------------------------------------------------------------------
__global__ __launch_bounds__(256) void k_scan1(const int* __restrict__ deg,
                                               int* __restrict__ bsum, int pad) {
    __shared__ int red[256];
    int t = threadIdx.x;
    int i = blockIdx.x * 256 + t;
    red[t] = (i < N_NODES) ? deg[i * pad] : 0;
    __syncthreads();
    for (int o = 128; o > 0; o >>= 1) {
        if (t < o) red[t] += red[t + o];
        __syncthreads();
    }
    if (t == 0) bsum[blockIdx.x] = red[0];
}

__global__ __launch_bounds__(256) void k_scan2(const int* __restrict__ bsum,
                                               int* __restrict__ boff) {
    __shared__ int part[256];
    int t = threadIdx.x;
    part[t] = (t < NB) ? bsum[t] : 0;
    __syncthreads();
    for (int o = 1; o < 256; o <<= 1) {
        int v = (t >= o) ? part[t - o] : 0;
        __syncthreads();
        part[t] += v;
        __syncthreads();
    }
    if (t < NB) boff[t] = (t == 0) ? 0 : part[t - 1];
}

__global__ __launch_bounds__(256) void k_scan3(const int* __restrict__ deg,
                                               const int* __restrict__ boff,
                                               int* __restrict__ off, int pad) {
    __shared__ int part[256];
    int t = threadIdx.x;
    int i = blockIdx.x * 256 + t;
    int d = (i < N_NODES) ? deg[i * pad] : 0;
    part[t] = d;
    __syncthreads();
    for (int o = 1; o < 256; o <<= 1) {
        int v = (t >= o) ? part[t - o] : 0;
        __syncthreads();
        part[t] += v;
        __syncthreads();
    }
    if (i < N_NODES) off[i] = boff[blockIdx.x] + part[t] - d;
    if (i == N_NODES - 1 && blockIdx.x == NB - 1) off[N_NODES] = N_EDGES;
}

// ---------------------------------------------------------------------------
__global__ __launch_bounds__(256) void k_fill(const int* __restrict__ ei,
                                              const int* __restrict__ off,
                                              const int* __restrict__ rank,
                                              int* __restrict__ col) {
    int idx = blockIdx.x * 256 + threadIdx.x;
    if (idx * 4 >= N_EDGES) return;
    int4 s = ((const int4*)ei)[idx];
    int4 d = ((const int4*)(ei + N_EDGES))[idx];
    int4 r = ((const int4*)rank)[idx];
    col[off[d.x] + r.x] = s.x;
    col[off[d.y] + r.y] = s.y;
    col[off[d.z] + r.z] = s.z;
    col[off[d.w] + r.w] = s.w;
}

// ---------------------------------------------------------------------------
// Fused aggregate + MFMA GEMM.
// Phase A: quarter-wave per node (16 lanes x 16B = one 256B bf16 row),
//          4 nodes in flight per wave, unroll-4. fp32 accumulate, mean,
//          pack bf16 -> LDS (MFMA A-operand friendly row-major).
// Phase B: 32x128 = 16 tiles of 16x16; wave wv does row-tile wv>>1,
//          col-half (wv&1)*64, 4 tiles x 4 K-steps of
//          mfma_f32_16x16x32_bf16 (fp32 accum). bias+relu epilogue.
// ---------------------------------------------------------------------------
__device__ inline void acc8(float* a, int4 u) {
    a[0] += __uint_as_float(((unsigned int)u.x) << 16);
    a[1] += __uint_as_float(((unsigned int)u.x) & 0xffff0000u);
    a[2] += __uint_as_float(((unsigned int)u.y) << 16);
    a[3] += __uint_as_float(((unsigned int)u.y) & 0xffff0000u);
    a[4] += __uint_as_float(((unsigned int)u.z) << 16);
    a[5] += __uint_as_float(((unsigned int)u.z) & 0xffff0000u);
    a[6] += __uint_as_float(((unsigned int)u.w) << 16);
    a[7] += __uint_as_float(((unsigned int)u.w) & 0xffff0000u);
}

__global__ __launch_bounds__(256) void k_agg_mfma(
    const float* __restrict__ x, const unsigned short* __restrict__ xh,
    const int* __restrict__ off, const int* __restrict__ col,
    const unsigned short* __restrict__ Wt, const float* __restrict__ bias,
    float* __restrict__ out) {
    __shared__ unsigned short HsB[ROWS * CH];  // 8 KB bf16 H tile
    const int t = threadIdx.x;
    const int wv = t >> 6;
    const int lane = t & 63;
    const int quad = lane >> 4;
    const int l16 = lane & 15;
    const int row0 = blockIdx.x * ROWS;
    const int c8 = l16 * 8;  // this lane's 8 channels

    // ---- Phase A ----
    #pragma unroll
    for (int kk = 0; kk < 2; ++kk) {
        const int ln = wv * 8 + kk * 4 + quad;
        const int n = row0 + ln;
        float a[8] = {0.f, 0.f, 0.f, 0.f, 0.f, 0.f, 0.f, 0.f};
        float inv = 1.0f;
        if (n < N_NODES) {
            const float* xr = x + (size_t)n * CH + c8;
            float4 s0 = *(const float4*)xr;
            float4 s1 = *(const float4*)(xr + 4);
            a[0] = s0.x; a[1] = s0.y; a[2] = s0.z; a[3] = s0.w;
            a[4] = s1.x; a[5] = s1.y; a[6] = s1.z; a[7] = s1.w;
            const int rb = off[n];
            const int re = off[n + 1];
            int j = rb;
            for (; j + 3 < re; j += 4) {
                int e0 = col[j], e1 = col[j + 1], e2 = col[j + 2], e3 = col[j + 3];
                int4 u0 = *(const int4*)(xh + (size_t)e0 * CH + c8);
                int4 u1 = *(const int4*)(xh + (size_t)e1 * CH + c8);
                int4 u2 = *(const int4*)(xh + (size_t)e2 * CH + c8);
                int4 u3 = *(const int4*)(xh + (size_t)e3 * CH + c8);
                acc8(a, u0); acc8(a, u1); acc8(a, u2); acc8(a, u3);
            }
            for (; j < re; ++j) {
                int4 u = *(const int4*)(xh + (size_t)col[j] * CH + c8);
                acc8(a, u);
            }
            inv = 1.0f / (float)(re - rb + 1);
        }
        int4 p;
        p.x = (int)(f2bf(a[0] * inv) | (f2bf(a[1] * inv) << 16));
        p.y = (int)(f2bf(a[2] * inv) | (f2bf(a[3] * inv) << 16));
        p.z = (int)(f2bf(a[4] * inv) | (f2bf(a[5] * inv) << 16));
        p.w = (int)(f2bf(a[6] * inv) | (f2bf(a[7] * inv) << 16));
        *(int4*)&HsB[ln * CH + c8] = p;
    }
    __syncthreads();

    // ---- Phase B: MFMA ----
    const int rt = wv >> 1;            // row tile 0..1 (16 rows each)
    const int cstart = (wv & 1) * 64;  // this wave's 64-col half
    f32x4 acc[4];
    #pragma unroll
    for (int tt = 0; tt < 4; ++tt) acc[tt] = (f32x4){0.f, 0.f, 0.f, 0.f};

    const unsigned short* hrow = &HsB[(rt * 16 + l16) * CH + quad * 8];
    #pragma unroll
    for (int ks = 0; ks < 4; ++ks) {
        bf16x8 af = *(const bf16x8*)(hrow + ks * 32);
        #pragma unroll
        for (int tt = 0; tt < 4; ++tt) {
            const int ncol = cstart + tt * 16 + l16;
            bf16x8 bf = *(const bf16x8*)(Wt + (size_t)ncol * CH + ks * 32 + quad * 8);
            acc[tt] = __builtin_amdgcn_mfma_f32_16x16x32_bf16(af, bf, acc[tt], 0, 0, 0);
        }
    }

    #pragma unroll
    for (int tt = 0; tt < 4; ++tt) {
        const int ncol = cstart + tt * 16 + l16;
        const float bv = bias[ncol];
        #pragma unroll
        for (int r = 0; r < 4; ++r) {
            const int row = row0 + rt * 16 + quad * 4 + r;
            if (row < N_NODES)
                out[(size_t)row * CH + ncol] = fmaxf(acc[tt][r] + bv, 0.f);
        }
    }
}

extern "C" void kernel_launch(void* const* d_in, const int* in_sizes, int n_in,
                              void* d_out, int out_size, void* d_ws, size_t ws_size,
                              hipStream_t stream) {
    const float* x    = (const float*)d_in[0];
    const int*   ei   = (const int*)d_in[1];
    const float* Wm   = (const float*)d_in[2];
    // d_in[3]=u, d_in[4]=c unused: softmax over HEADS=1 is identically 1.0
    const float* bias = (const float*)d_in[5];
    float* out = (float*)d_out;

    const size_t xh_bytes = (size_t)N_NODES * CH * 2;  // 12.8 MB
    const size_t wt_bytes = (size_t)CH * CH * 2;       // 32 KB
    const size_t base = xh_bytes + wt_bytes;
    const size_t fixed_ints = (size_t)(N_NODES + 1 + 2 * N_EDGES + 2 * NB);
    const size_t fixed_bytes = fixed_ints * 4;

    // counter padding tier from remaining scratch
    int pad = 1;
    if (ws_size >= base + fixed_bytes + (size_t)N_NODES * 32 * 4) pad = 32;
    else if (ws_size >= base + fixed_bytes + (size_t)N_NODES * 16 * 4) pad = 16;
    else if (ws_size >= base + fixed_bytes + (size_t)N_NODES * 8 * 4) pad = 8;
    const int degN = ((N_NODES * pad + 3) / 4) * 4;

    unsigned short* xh = (unsigned short*)d_ws;
    unsigned short* Wt = (unsigned short*)((char*)d_ws + xh_bytes);
    int* wsi  = (int*)((char*)d_ws + base);
    int* deg  = wsi;
    int* off  = deg + degN;
    int* rank = off + N_NODES + 1;
    int* col  = rank + N_EDGES;
    int* bsum = col + N_EDGES;
    int* boff = bsum + NB;

    k_prep<<<dim3((N_NODES * CH / 4 + 255) / 256), dim3(256), 0, stream>>>(
        x, Wm, xh, Wt, deg, degN);
    k_hist<<<dim3((N_EDGES / 4 + 255) / 256), dim3(256), 0, stream>>>(ei, deg, rank, pad);
    k_scan1<<<dim3(NB), dim3(256), 0, stream>>>(deg, bsum, pad);
    k_scan2<<<dim3(1), dim3(256), 0, stream>>>(bsum, boff);
    k_scan3<<<dim3(NB), dim3(256), 0, stream>>>(deg, boff, off, pad);
    k_fill<<<dim3((N_EDGES / 4 + 255) / 256), dim3(256), 0, stream>>>(ei, off, rank, col);
    k_agg_mfma<<<dim3((N_NODES + ROWS - 1) / ROWS), dim3(256), 0, stream>>>(
        x, xh, off, col, Wt, bias, out);
}

// Round 7
// 163.505 us; speedup vs baseline: 7.0957x; 1.0928x over previous
//
#include <hip/hip_runtime.h>

#define N_NODES 50000
#define N_EDGES 600000
#define CH 128
#define ROWS 32
#define MD 32          // ELL width (Poisson(12) tail: P(deg>32) ~ 1e-7)
#define SPILL_CAP 65536
#define HSTRIDE 136    // LDS H-tile row stride in shorts (272 B -> 2-way bank aliasing, free)

typedef __attribute__((ext_vector_type(8))) short bf16x8;
typedef __attribute__((ext_vector_type(4))) float f32x4;

// fp32 -> bf16 RNE
__device__ inline unsigned int f2bf(float f) {
    unsigned int b = __float_as_uint(f);
    unsigned int r = b + 0x7fffu + ((b >> 16) & 1u);
    return r >> 16;
}

__device__ inline void acc8(float* a, int4 u) {
    a[0] += __uint_as_float(((unsigned int)u.x) << 16);
    a[1] += __uint_as_float(((unsigned int)u.x) & 0xffff0000u);
    a[2] += __uint_as_float(((unsigned int)u.y) << 16);
    a[3] += __uint_as_float(((unsigned int)u.y) & 0xffff0000u);
    a[4] += __uint_as_float(((unsigned int)u.z) << 16);
    a[5] += __uint_as_float(((unsigned int)u.z) & 0xffff0000u);
    a[6] += __uint_as_float(((unsigned int)u.w) << 16);
    a[7] += __uint_as_float(((unsigned int)u.w) & 0xffff0000u);
}

// ---------------------------------------------------------------------------
// D1: prep — zero deg + spill counter, x -> bf16, W -> bf16 transposed
// ---------------------------------------------------------------------------
__global__ __launch_bounds__(256) void k_prep(const float* __restrict__ x,
                                              const float* __restrict__ Wm,
                                              unsigned short* __restrict__ xh,
                                              unsigned short* __restrict__ Wt,
                                              int* __restrict__ deg, int degN,
                                              int* __restrict__ spill_cnt) {
    int i = blockIdx.x * 256 + threadIdx.x;
    const int NX4 = N_NODES * CH / 4;  // 1.6M float4
    if (i < NX4) {
        float4 v = ((const float4*)x)[i];
        ushort4 o;
        o.x = (unsigned short)f2bf(v.x);
        o.y = (unsigned short)f2bf(v.y);
        o.z = (unsigned short)f2bf(v.z);
        o.w = (unsigned short)f2bf(v.w);
        ((ushort4*)xh)[i] = o;
    }
    if (i < degN / 4) ((int4*)deg)[i] = make_int4(0, 0, 0, 0);
    if (i < CH * CH) {
        int n = i >> 7, k = i & 127;
        Wt[n * CH + k] = (unsigned short)f2bf(Wm[k * CH + n]);
    }
    if (i == 0) *spill_cnt = 0;
}

// ---------------------------------------------------------------------------
// D2: histfill — rank = deg[dst]++; ell[dst*MD + rank] = src (spill if > MD)
// ---------------------------------------------------------------------------
__global__ __launch_bounds__(256) void k_histfill(const int* __restrict__ ei,
                                                  int* __restrict__ deg, int pad,
                                                  int* __restrict__ ell,
                                                  int* __restrict__ spill_cnt,
                                                  int* __restrict__ spill) {
    int idx = blockIdx.x * 256 + threadIdx.x;  // int4 index
    if (idx * 4 >= N_EDGES) return;
    int4 s = ((const int4*)ei)[idx];
    int4 d = ((const int4*)(ei + N_EDGES))[idx];
    #pragma unroll
    for (int q = 0; q < 4; ++q) {
        int src = (q == 0) ? s.x : (q == 1) ? s.y : (q == 2) ? s.z : s.w;
        int dst = (q == 0) ? d.x : (q == 1) ? d.y : (q == 2) ? d.z : d.w;
        int r = atomicAdd(&deg[dst * pad], 1);
        if (r < MD) {
            ell[dst * MD + r] = src;
        } else {
            int p = atomicAdd(spill_cnt, 1);
            if (p < SPILL_CAP) {
                spill[2 * p] = src;
                spill[2 * p + 1] = dst;
            }
        }
    }
}

// ---------------------------------------------------------------------------
// D3: fused pull-aggregate (bf16 ELL gather) + MFMA GEMM + bias + relu.
// Phase A: quarter-wave per node (16 lanes x 8ch), fp32 accumulate, mean,
//          pack bf16 -> LDS (row stride 136 shorts: conflict-free).
// Phase B: 32x128 tile via mfma_f32_16x16x32_bf16, wave wv -> row-tile wv>>1,
//          col-half (wv&1)*64.
// ---------------------------------------------------------------------------
__global__ __launch_bounds__(256) void k_agg_mfma(
    const unsigned short* __restrict__ xh, const int* __restrict__ deg, int pad,
    const int* __restrict__ ell, const int* __restrict__ spill_cnt,
    const int* __restrict__ spill, const unsigned short* __restrict__ Wt,
    const float* __restrict__ bias, float* __restrict__ out) {
    __shared__ __align__(16) unsigned short HsB[ROWS * HSTRIDE];
    const int t = threadIdx.x;
    const int wv = t >> 6;
    const int lane = t & 63;
    const int quad = lane >> 4;
    const int l16 = lane & 15;
    const int row0 = blockIdx.x * ROWS;
    const int c8 = l16 * 8;  // this lane's 8 channels

    // ---- Phase A ----
    #pragma unroll
    for (int kk = 0; kk < 2; ++kk) {
        const int ln = wv * 8 + kk * 4 + quad;
        const int n = row0 + ln;
        float a[8] = {0.f, 0.f, 0.f, 0.f, 0.f, 0.f, 0.f, 0.f};
        float inv = 1.0f;
        if (n < N_NODES) {
            // self-loop from bf16 copy
            acc8(a, *(const int4*)(xh + (size_t)n * CH + c8));
            const int d = deg[n * pad];
            const int dl = (d < MD) ? d : MD;
            const int* cl = ell + (size_t)n * MD;
            int j = 0;
            for (; j + 3 < dl; j += 4) {
                int e0 = cl[j], e1 = cl[j + 1], e2 = cl[j + 2], e3 = cl[j + 3];
                int4 u0 = *(const int4*)(xh + (size_t)e0 * CH + c8);
                int4 u1 = *(const int4*)(xh + (size_t)e1 * CH + c8);
                int4 u2 = *(const int4*)(xh + (size_t)e2 * CH + c8);
                int4 u3 = *(const int4*)(xh + (size_t)e3 * CH + c8);
                acc8(a, u0); acc8(a, u1); acc8(a, u2); acc8(a, u3);
            }
            for (; j < dl; ++j)
                acc8(a, *(const int4*)(xh + (size_t)cl[j] * CH + c8));
            // spill pass (expected count: 0)
            int sc = *spill_cnt;
            if (sc > SPILL_CAP) sc = SPILL_CAP;
            for (int sidx = 0; sidx < sc; ++sidx) {
                if (spill[2 * sidx + 1] == n)
                    acc8(a, *(const int4*)(xh + (size_t)spill[2 * sidx] * CH + c8));
            }
            inv = 1.0f / (float)(d + 1);
        }
        int4 p;
        p.x = (int)(f2bf(a[0] * inv) | (f2bf(a[1] * inv) << 16));
        p.y = (int)(f2bf(a[2] * inv) | (f2bf(a[3] * inv) << 16));
        p.z = (int)(f2bf(a[4] * inv) | (f2bf(a[5] * inv) << 16));
        p.w = (int)(f2bf(a[6] * inv) | (f2bf(a[7] * inv) << 16));
        *(int4*)&HsB[ln * HSTRIDE + c8] = p;
    }
    __syncthreads();

    // ---- Phase B: MFMA ----
    const int rt = wv >> 1;            // row tile 0..1 (16 rows)
    const int cstart = (wv & 1) * 64;  // 64-col half
    f32x4 acc[4];
    #pragma unroll
    for (int tt = 0; tt < 4; ++tt) acc[tt] = (f32x4){0.f, 0.f, 0.f, 0.f};

    const unsigned short* hrow = &HsB[(rt * 16 + l16) * HSTRIDE + quad * 8];
    #pragma unroll
    for (int ks = 0; ks < 4; ++ks) {
        bf16x8 af = *(const bf16x8*)(hrow + ks * 32);
        #pragma unroll
        for (int tt = 0; tt < 4; ++tt) {
            const int ncol = cstart + tt * 16 + l16;
            bf16x8 bf = *(const bf16x8*)(Wt + (size_t)ncol * CH + ks * 32 + quad * 8);
            acc[tt] = __builtin_amdgcn_mfma_f32_16x16x32_bf16(af, bf, acc[tt], 0, 0, 0);
        }
    }

    #pragma unroll
    for (int tt = 0; tt < 4; ++tt) {
        const int ncol = cstart + tt * 16 + l16;
        const float bv = bias[ncol];
        #pragma unroll
        for (int r = 0; r < 4; ++r) {
            const int row = row0 + rt * 16 + quad * 4 + r;
            if (row < N_NODES)
                out[(size_t)row * CH + ncol] = fmaxf(acc[tt][r] + bv, 0.f);
        }
    }
}

extern "C" void kernel_launch(void* const* d_in, const int* in_sizes, int n_in,
                              void* d_out, int out_size, void* d_ws, size_t ws_size,
                              hipStream_t stream) {
    const float* x    = (const float*)d_in[0];
    const int*   ei   = (const int*)d_in[1];
    const float* Wm   = (const float*)d_in[2];
    // d_in[3]=u, d_in[4]=c unused: softmax over HEADS=1 is identically 1.0
    const float* bias = (const float*)d_in[5];
    float* out = (float*)d_out;

    const size_t xh_bytes   = (size_t)N_NODES * CH * 2;       // 12.8 MB
    const size_t wt_bytes   = (size_t)CH * CH * 2;            // 32 KB
    const size_t ell_bytes  = (size_t)N_NODES * MD * 4;       // 6.4 MB
    const size_t spill_bytes = (size_t)(1 + 2 * SPILL_CAP) * 4;
    const size_t fixed = xh_bytes + wt_bytes + ell_bytes + spill_bytes;

    // counter padding tier from remaining scratch
    int pad = 1;
    if (ws_size >= fixed + (size_t)N_NODES * 32 * 4) pad = 32;
    else if (ws_size >= fixed + (size_t)N_NODES * 8 * 4) pad = 8;
    const int degN = ((N_NODES * pad + 3) / 4) * 4;

    unsigned short* xh = (unsigned short*)d_ws;
    unsigned short* Wt = (unsigned short*)((char*)d_ws + xh_bytes);
    int* ell       = (int*)((char*)d_ws + xh_bytes + wt_bytes);
    int* spill_cnt = ell + (size_t)N_NODES * MD;
    int* spill     = spill_cnt + 1;
    int* deg       = spill + 2 * SPILL_CAP;

    k_prep<<<dim3((N_NODES * CH / 4 + 255) / 256), dim3(256), 0, stream>>>(
        x, Wm, xh, Wt, deg, degN, spill_cnt);
    k_histfill<<<dim3((N_EDGES / 4 + 255) / 256), dim3(256), 0, stream>>>(
        ei, deg, pad, ell, spill_cnt, spill);
    k_agg_mfma<<<dim3((N_NODES + ROWS - 1) / ROWS), dim3(256), 0, stream>>>(
        xh, deg, pad, ell, spill_cnt, spill, Wt, bias, out);
}